// Round 5
// baseline (57.497 us; speedup 1.0000x reference)
//
#include <hip/hip_runtime.h>
#include <hip/hip_fp16.h>

#define FS 32
#define NS 30               // num_sample
#define FDIM 256
#define NXCD 8
#define SLABW 32            // floats per slab (gather output view)
#define SLABH 32            // halves per slab row = 64 B in t16
#define BPB 64              // output rows (b) per block

// ---------- Pass 1: re-layout f32 [nrow][256] -> f16 slab-major [8][nrow][32]
// Pure streaming both sides: wave reads one full row (64 lanes x float4),
// each lane writes its 8 B to its slab's contiguous array.
__global__ __launch_bounds__(256) void stc_relayout_f16(
    const float* __restrict__ feat, __half* __restrict__ t16, int nrow)
{
    const int wave = threadIdx.x >> 6, lane = threadIdx.x & 63;
    const int slab = lane >> 3, oct = lane & 7;
    const int gw0  = blockIdx.x * 4 + wave;
    const int nw   = gridDim.x * 4;
    for (int row = gw0; row < nrow; row += nw) {
        const float4 v = *((const float4*)(feat + (long long)row * FDIM) + lane);
        __half2 h01 = __floats2half2_rn(v.x, v.y);
        __half2 h23 = __floats2half2_rn(v.z, v.w);
        uint2 u;
        u.x = *reinterpret_cast<unsigned int*>(&h01);
        u.y = *reinterpret_cast<unsigned int*>(&h23);
        *(uint2*)(t16 + ((long long)slab * nrow + row) * SLABH + oct * 4) = u;
    }
}

// ---------- Pass 2: gather-reduce from slab-major f16.
// slab == blockIdx%8 == XCD: compulsory misses are an ASCENDING sweep of a
// contiguous 6.4 MB slab (streaming); reuse window ~2.2 MB fits per-XCD L2.
__global__ __launch_bounds__(256, 5) void stc_gather_f16(
    const __half* __restrict__ t16,     // [8][nrow][32]
    const int*   __restrict__ nidx,     // [B, 30]
    const float* __restrict__ weight,   // [32]
    const float* __restrict__ avgw,     // [32]
    const float* __restrict__ U,        // [32, 32]
    float* __restrict__ out,            // [B, 256]
    int B, int nrow)
{
    __shared__ float t_sh[FS];
    __shared__ float c_sh[FS];
    __shared__ int   idx_sh[BPB * NS];
    __shared__ int   sidx_sh[BPB * NS];
    __shared__ float scoef_sh[BPB * NS];

    const int tid   = threadIdx.x;
    const int slab  = blockIdx.x & (NXCD - 1);
    const int chunk = blockIdx.x >> 3;
    const int b0    = chunk * BPB;

    if (tid < FS) {
        float t = 0.f;
        #pragma unroll
        for (int f = 0; f < FS; ++f) t += U[f * FS + tid] * avgw[f];
        t_sh[tid] = t * weight[tid];
    }
    for (int i = tid; i < BPB * NS; i += 256) {
        int g = b0 * NS + i;
        idx_sh[i] = (g < B * NS) ? nidx[g] : 0;
    }
    __syncthreads();
    if (tid < FS) {
        float c = 0.f;
        #pragma unroll
        for (int g = 0; g < FS; ++g) c += U[tid * FS + g] * t_sh[g];
        c_sh[tid] = c;
    }
    __syncthreads();

    // Per-b rank-sort of 30 (idx, coef) pairs ascending by idx.
    for (int j = tid; j < BPB * NS; j += 256) {
        const int bl = j / NS, s = j - bl * NS;
        const int base = bl * NS;
        const int key = idx_sh[base + s];
        int rank = 0;
        #pragma unroll
        for (int m = 0; m < NS; ++m) {
            const int km = idx_sh[base + m];
            rank += (km < key) || (km == key && m < s);
        }
        sidx_sh[base + rank]  = key;
        scoef_sh[base + rank] = c_sh[s + 1];   // slots 0 and 31 zero-padded
    }
    __syncthreads();

    // thread = (bl 0..31, oct 0..7); 8 threads x 8 B = one 64 B slab row.
    // Each thread handles b0+bl and b0+bl+32: two independent load chains.
    const int bl = tid >> 3, oct = tid & 3 | (tid & 7 & ~3) ? tid & 7 : tid & 7; // oct = tid & 7
    const int o  = tid & 7;
    const __half* fbase = t16 + (long long)slab * nrow * SLABH + o * 4;
    const int s0 = bl * NS;
    const int s1 = (bl + 32) * NS;

    float4 a0 = make_float4(0.f, 0.f, 0.f, 0.f);
    float4 a1 = make_float4(0.f, 0.f, 0.f, 0.f);

    #pragma unroll 6
    for (int s = 0; s < NS; ++s) {
        const int   r0 = sidx_sh[s0 + s];
        const float c0 = scoef_sh[s0 + s];
        const int   r1 = sidx_sh[s1 + s];
        const float c1 = scoef_sh[s1 + s];
        float2 raw0 = *(const float2*)(fbase + ((long long)r0 << 5));
        float2 raw1 = *(const float2*)(fbase + ((long long)r1 << 5));
        const __half2 h0a = *reinterpret_cast<__half2*>(&raw0.x);
        const __half2 h0b = *reinterpret_cast<__half2*>(&raw0.y);
        const __half2 h1a = *reinterpret_cast<__half2*>(&raw1.x);
        const __half2 h1b = *reinterpret_cast<__half2*>(&raw1.y);
        const float2 f0a = __half22float2(h0a), f0b = __half22float2(h0b);
        const float2 f1a = __half22float2(h1a), f1b = __half22float2(h1b);
        a0.x += c0 * f0a.x;  a0.y += c0 * f0a.y;
        a0.z += c0 * f0b.x;  a0.w += c0 * f0b.y;
        a1.x += c1 * f1a.x;  a1.y += c1 * f1a.y;
        a1.z += c1 * f1b.x;  a1.w += c1 * f1b.y;
    }

    const int bA = b0 + bl, bB = b0 + bl + 32;
    if (bA < B) *((float4*)(out + (long long)bA * FDIM + slab * SLABW) + o) = a0;
    if (bB < B) *((float4*)(out + (long long)bB * FDIM + slab * SLABW) + o) = a1;
}

// ---------- Fallback (R4 kernel): direct f32 gather, used if ws too small.
__global__ __launch_bounds__(256, 5) void stc_slab128_kernel(
    const float* __restrict__ feat, const int* __restrict__ nidx,
    const float* __restrict__ weight, const float* __restrict__ avgw,
    const float* __restrict__ U, float* __restrict__ out, int B)
{
    __shared__ float t_sh[FS];
    __shared__ float c_sh[FS];
    __shared__ int   idx_sh[BPB * NS];
    __shared__ int   sidx_sh[BPB * NS];
    __shared__ float scoef_sh[BPB * NS];

    const int tid   = threadIdx.x;
    const int slab  = blockIdx.x & (NXCD - 1);
    const int chunk = blockIdx.x >> 3;
    const int b0    = chunk * BPB;

    if (tid < FS) {
        float t = 0.f;
        #pragma unroll
        for (int f = 0; f < FS; ++f) t += U[f * FS + tid] * avgw[f];
        t_sh[tid] = t * weight[tid];
    }
    for (int i = tid; i < BPB * NS; i += 256) {
        int g = b0 * NS + i;
        idx_sh[i] = (g < B * NS) ? nidx[g] : 0;
    }
    __syncthreads();
    if (tid < FS) {
        float c = 0.f;
        #pragma unroll
        for (int g = 0; g < FS; ++g) c += U[tid * FS + g] * t_sh[g];
        c_sh[tid] = c;
    }
    __syncthreads();
    for (int j = tid; j < BPB * NS; j += 256) {
        const int bl = j / NS, s = j - bl * NS;
        const int base = bl * NS;
        const int key = idx_sh[base + s];
        int rank = 0;
        #pragma unroll
        for (int m = 0; m < NS; ++m) {
            const int km = idx_sh[base + m];
            rank += (km < key) || (km == key && m < s);
        }
        sidx_sh[base + rank]  = key;
        scoef_sh[base + rank] = c_sh[s + 1];
    }
    __syncthreads();

    const int bl = tid >> 3, q = tid & 7;
    const float* fbase = feat + slab * SLABW + q * 4;
    const int s0 = bl * NS, s1 = (bl + 32) * NS;
    float4 a0 = make_float4(0.f, 0.f, 0.f, 0.f);
    float4 a1 = make_float4(0.f, 0.f, 0.f, 0.f);
    #pragma unroll 6
    for (int s = 0; s < NS; ++s) {
        const int   r0 = sidx_sh[s0 + s];
        const float c0 = scoef_sh[s0 + s];
        const int   r1 = sidx_sh[s1 + s];
        const float c1 = scoef_sh[s1 + s];
        const float4 v0 = *(const float4*)(fbase + (long long)r0 * FDIM);
        const float4 v1 = *(const float4*)(fbase + (long long)r1 * FDIM);
        a0.x += c0 * v0.x;  a0.y += c0 * v0.y;
        a0.z += c0 * v0.z;  a0.w += c0 * v0.w;
        a1.x += c1 * v1.x;  a1.y += c1 * v1.y;
        a1.z += c1 * v1.z;  a1.w += c1 * v1.w;
    }
    const int bA = b0 + bl, bB = b0 + bl + 32;
    if (bA < B) *((float4*)(out + (long long)bA * FDIM + slab * SLABW) + q) = a0;
    if (bB < B) *((float4*)(out + (long long)bB * FDIM + slab * SLABW) + q) = a1;
}

extern "C" void kernel_launch(void* const* d_in, const int* in_sizes, int n_in,
                              void* d_out, int out_size, void* d_ws, size_t ws_size,
                              hipStream_t stream) {
    const float* feat   = (const float*)d_in[0];
    const int*   nidx   = (const int*)d_in[1];
    const float* weight = (const float*)d_in[2];
    const float* avgw   = (const float*)d_in[3];
    const float* U      = (const float*)d_in[4];
    float* out = (float*)d_out;

    const int B    = in_sizes[1] / NS;        // 10000
    const int nrow = in_sizes[0] / FDIM;      // 100000
    const int chunks = (B + BPB - 1) / BPB;   // 157
    const int grid   = chunks * NXCD;         // 1256

    const size_t need = (size_t)NXCD * nrow * SLABH * sizeof(__half); // 51.2 MB
    if (ws_size >= need) {
        __half* t16 = (__half*)d_ws;
        stc_relayout_f16<<<2048, 256, 0, stream>>>(feat, t16, nrow);
        stc_gather_f16<<<grid, 256, 0, stream>>>(t16, nidx, weight, avgw, U, out, B, nrow);
    } else {
        stc_slab128_kernel<<<grid, 256, 0, stream>>>(feat, nidx, weight, avgw, U, out, B);
    }
}

// Round 6
// 47.487 us; speedup vs baseline: 1.2108x; 1.2108x over previous
//
#include <hip/hip_runtime.h>

#define FS 32
#define NS 30               // num_sample
#define FDIM 256
#define NXCD 8
#define QW 64               // floats per quarter-slab = 256 B
#define BPB 32              // output rows (b) per block

// Quarter-row (256 B) slab gather. slab = xcd&3: each slab's table bytes are
// cached by 2 XCDs; sorted per-b sweep keeps the instantaneous window ~4.6 MB
// per XCD (~L2 size). 256 B granule probes the fabric's granule-rate curve
// (R4's 128 B ran ~2 TB/s; 1 KB runs 6.2 TB/s).
__global__ __launch_bounds__(256, 6) void stc_q256_kernel(
    const float* __restrict__ feat,     // [100000, 256]
    const int*   __restrict__ nidx,     // [B, 30]
    const float* __restrict__ weight,   // [32]
    const float* __restrict__ avgw,     // [32]
    const float* __restrict__ U,        // [32, 32]
    float* __restrict__ out,            // [B, 256]
    int B, int chunks)
{
    __shared__ float t_sh[FS];
    __shared__ float c_sh[FS];
    __shared__ int   idx_sh[BPB * NS];
    __shared__ int   sidx_sh[BPB * NS];
    __shared__ float scoef_sh[BPB * NS];

    const int tid   = threadIdx.x;
    const int xcd   = blockIdx.x & (NXCD - 1);   // dispatch round-robin -> XCD id
    const int slab  = xcd & 3;                   // 4 quarter-slabs, 2 XCDs each
    const int chunk = (blockIdx.x >> 3) * 2 + (xcd >> 2);
    if (chunk >= chunks) return;                 // block-uniform, before barriers
    const int b0 = chunk * BPB;

    // t[g] = weight[g] * sum_f U[f][g]*avg[f]
    if (tid < FS) {
        float t = 0.f;
        #pragma unroll
        for (int f = 0; f < FS; ++f) t += U[f * FS + tid] * avgw[f];
        t_sh[tid] = t * weight[tid];
    }
    // stage this chunk's neighbor indices (coalesced)
    for (int i = tid; i < BPB * NS; i += 256) {
        int g = b0 * NS + i;
        idx_sh[i] = (g < B * NS) ? nidx[g] : 0;
    }
    __syncthreads();
    // c[f'] = sum_g U[f'][g] * t[g]
    if (tid < FS) {
        float c = 0.f;
        #pragma unroll
        for (int g = 0; g < FS; ++g) c += U[tid * FS + g] * t_sh[g];
        c_sh[tid] = c;
    }
    __syncthreads();

    // Per-b rank-sort of 30 (idx, coef) pairs ascending by idx.
    for (int j = tid; j < BPB * NS; j += 256) {
        const int bl = j / NS, s = j - bl * NS;
        const int base = bl * NS;
        const int key = idx_sh[base + s];
        int rank = 0;
        #pragma unroll
        for (int m = 0; m < NS; ++m) {
            const int km = idx_sh[base + m];
            rank += (km < key) || (km == key && m < s);
        }
        sidx_sh[base + rank]  = key;
        scoef_sh[base + rank] = c_sh[s + 1];   // slots 0 and 31 zero-padded
    }
    __syncthreads();

    // Gather-reduce: thread = (bl 0..15, q 0..15); 16 threads x float4 = one
    // 256 B quarter-row. Each thread handles b0+bl and b0+bl+16 -> two
    // independent load chains for MLP.
    const int bl = tid >> 4;
    const int q  = tid & 15;
    const float* fbase = feat + slab * QW + q * 4;
    const int s0 = bl * NS;
    const int s1 = (bl + 16) * NS;

    float4 a0 = make_float4(0.f, 0.f, 0.f, 0.f);
    float4 a1 = make_float4(0.f, 0.f, 0.f, 0.f);

    #pragma unroll 6
    for (int s = 0; s < NS; ++s) {
        const int   r0 = sidx_sh[s0 + s];
        const float c0 = scoef_sh[s0 + s];
        const int   r1 = sidx_sh[s1 + s];
        const float c1 = scoef_sh[s1 + s];
        const float4 v0 = *(const float4*)(fbase + (long long)r0 * FDIM);
        const float4 v1 = *(const float4*)(fbase + (long long)r1 * FDIM);
        a0.x += c0 * v0.x;  a0.y += c0 * v0.y;
        a0.z += c0 * v0.z;  a0.w += c0 * v0.w;
        a1.x += c1 * v1.x;  a1.y += c1 * v1.y;
        a1.z += c1 * v1.z;  a1.w += c1 * v1.w;
    }

    const int bA = b0 + bl, bB = b0 + bl + 16;
    if (bA < B) *((float4*)(out + (long long)bA * FDIM + slab * QW) + q) = a0;
    if (bB < B) *((float4*)(out + (long long)bB * FDIM + slab * QW) + q) = a1;
}

extern "C" void kernel_launch(void* const* d_in, const int* in_sizes, int n_in,
                              void* d_out, int out_size, void* d_ws, size_t ws_size,
                              hipStream_t stream) {
    const float* feat   = (const float*)d_in[0];
    const int*   nidx   = (const int*)d_in[1];
    const float* weight = (const float*)d_in[2];
    const float* avgw   = (const float*)d_in[3];
    const float* U      = (const float*)d_in[4];
    float* out = (float*)d_out;

    const int B      = in_sizes[1] / NS;            // 10000
    const int chunks = (B + BPB - 1) / BPB;         // 313
    const int grid   = ((chunks + 1) / 2) * NXCD;   // 157 * 8 = 1256

    stc_q256_kernel<<<grid, 256, 0, stream>>>(feat, nidx, weight, avgw, U, out, B, chunks);
}